// Round 1
// baseline (1968.487 us; speedup 1.0000x reference)
//
#include <hip/hip_runtime.h>
#include <math.h>

#define NB 2
#define NS 8192
#define NE 128
#define NROWS (NB * NS)

// LDS strides (floats). Chosen so float4 reads stay 16B-aligned.
#define WTS 68   // Wt [128 e][64 o]
#define XTS 36   // xT [128 e][32 r]
#define QTS 36   // QT [128 e][32 q]
#define KTS 68   // KT [128 e][64 k]   (region shared with V)
#define VTS 132  // V  [64 k][128 d]   (region shared with KT)
#define PTS 36   // PT [64 k][32 q]

// ---------------------------------------------------------------------------
// QKV projection: out[row][o] = sum_e x[row][e] * W[o][e] + b[o]
// grid (NROWS/32, 3, 2), block 256. Block: 32 rows x 64 o-cols of one matrix.
// ---------------------------------------------------------------------------
__global__ __launch_bounds__(256, 2)
void qkv_kernel(const float* __restrict__ x,
                const float* __restrict__ Wq, const float* __restrict__ bq,
                const float* __restrict__ Wk, const float* __restrict__ bk,
                const float* __restrict__ Wv, const float* __restrict__ bv,
                float* __restrict__ qkv)
{
    __shared__ float Wt[128 * WTS];
    __shared__ float xT[128 * XTS];

    const int t    = threadIdx.x;
    const int row0 = blockIdx.x * 32;
    const int mat  = blockIdx.y;       // 0=Q 1=K 2=V
    const int oh   = blockIdx.z * 64;  // o-half

    const float* W    = (mat == 0) ? Wq : (mat == 1) ? Wk : Wv;
    const float* bias = (mat == 0) ? bq : (mat == 1) ? bk : bv;
    float* out = qkv + (size_t)mat * NROWS * NE;

    // Stage W half (64 o-rows x 128 e), transposed -> Wt[e][o]
    #pragma unroll
    for (int i = 0; i < 8; ++i) {
        int v  = t + i * 256;          // float4 index, 2048 total
        int ol = v >> 5;               // 0..63
        int e0 = (v & 31) * 4;
        float4 w4 = *(const float4*)&W[(size_t)(oh + ol) * NE + e0];
        Wt[(e0 + 0) * WTS + ol] = w4.x;
        Wt[(e0 + 1) * WTS + ol] = w4.y;
        Wt[(e0 + 2) * WTS + ol] = w4.z;
        Wt[(e0 + 3) * WTS + ol] = w4.w;
    }
    // Stage x tile (32 rows x 128 e), transposed -> xT[e][r]
    #pragma unroll
    for (int i = 0; i < 4; ++i) {
        int v  = t + i * 256;          // 1024 total
        int r  = v >> 5;               // 0..31
        int e0 = (v & 31) * 4;
        float4 x4 = *(const float4*)&x[(size_t)(row0 + r) * NE + e0];
        xT[(e0 + 0) * XTS + r] = x4.x;
        xT[(e0 + 1) * XTS + r] = x4.y;
        xT[(e0 + 2) * XTS + r] = x4.z;
        xT[(e0 + 3) * XTS + r] = x4.w;
    }
    __syncthreads();

    const int tr = t >> 4;   // 0..15
    const int to = t & 15;   // 0..15
    const int r0 = tr * 2;
    const int o0 = to * 4;

    float acc[2][4] = {};
    #pragma unroll 8
    for (int e = 0; e < 128; ++e) {
        float2 xv = *(const float2*)&xT[e * XTS + r0];
        float4 wv = *(const float4*)&Wt[e * WTS + o0];
        acc[0][0] = fmaf(xv.x, wv.x, acc[0][0]);
        acc[0][1] = fmaf(xv.x, wv.y, acc[0][1]);
        acc[0][2] = fmaf(xv.x, wv.z, acc[0][2]);
        acc[0][3] = fmaf(xv.x, wv.w, acc[0][3]);
        acc[1][0] = fmaf(xv.y, wv.x, acc[1][0]);
        acc[1][1] = fmaf(xv.y, wv.y, acc[1][1]);
        acc[1][2] = fmaf(xv.y, wv.z, acc[1][2]);
        acc[1][3] = fmaf(xv.y, wv.w, acc[1][3]);
    }

    float4 bb = *(const float4*)&bias[oh + o0];
    #pragma unroll
    for (int i = 0; i < 2; ++i) {
        float4 r;
        r.x = acc[i][0] + bb.x;
        r.y = acc[i][1] + bb.y;
        r.z = acc[i][2] + bb.z;
        r.w = acc[i][3] + bb.w;
        *(float4*)&out[(size_t)(row0 + r0 + i) * NE + oh + o0] = r;
    }
}

// ---------------------------------------------------------------------------
// Flash attention, fp32. grid (NS/32, NB), block 256.
// Block owns 32 q-rows; iterates 128 key-tiles of 64.
// LDS: QT 18432B + shared KT/V region 34816B + PT 9216B = 62464B (2 blk/CU).
// ---------------------------------------------------------------------------
__global__ __launch_bounds__(256, 2)
void attn_kernel(const float* __restrict__ qkv, float* __restrict__ outp)
{
    __shared__ float QT[128 * QTS];     // [e][q], q pre-scaled by 1/sqrt(E)
    __shared__ float KV[128 * KTS];     // KT [e][k]  OR  V [k][d] (time-shared)
    __shared__ float PT[64 * PTS];      // [k][q]

    const int t  = threadIdx.x;
    const int qt = blockIdx.x;
    const int b  = blockIdx.y;

    const float* Q = qkv;
    const float* K = qkv + (size_t)NROWS * NE;
    const float* V = qkv + (size_t)2 * NROWS * NE;

    const int qrow0 = b * NS + qt * 32;

    // Stage Q tile transposed, folding in 1/sqrt(128)
    const float sc = 0.08838834764831845f;
    #pragma unroll
    for (int i = 0; i < 4; ++i) {
        int v  = t + i * 256;
        int r  = v >> 5;
        int e0 = (v & 31) * 4;
        float4 q4 = *(const float4*)&Q[(size_t)(qrow0 + r) * NE + e0];
        QT[(e0 + 0) * QTS + r] = q4.x * sc;
        QT[(e0 + 1) * QTS + r] = q4.y * sc;
        QT[(e0 + 2) * QTS + r] = q4.z * sc;
        QT[(e0 + 3) * QTS + r] = q4.w * sc;
    }

    const int tq = t >> 4;    // 0..15 -> q0 = 2*tq
    const int tk = t & 15;    // k-group (GEMM1) / d-group (GEMM2)
    const int q0 = tq * 2;
    const int k0 = tk * 4;
    const int d0 = tk * 8;

    float m[2] = {-INFINITY, -INFINITY};
    float l[2] = {0.f, 0.f};
    float O[2][8] = {};

    for (int kt = 0; kt < NS / 64; ++kt) {
        // ---- issue global loads early (hide behind prev GEMM2) ----
        const size_t kbase = ((size_t)b * NS + kt * 64) * NE;
        float4 kreg[8], vreg[8];
        #pragma unroll
        for (int i = 0; i < 8; ++i) {
            int v  = t + i * 256;      // 2048 float4 per 64x128 tile
            int r  = v >> 5;           // 0..63
            int e0 = (v & 31) * 4;
            kreg[i] = *(const float4*)&K[kbase + (size_t)r * NE + e0];
            vreg[i] = *(const float4*)&V[kbase + (size_t)r * NE + e0];
        }

        __syncthreads();   // prev iteration's GEMM2 done with KV/PT

        // ---- write KT (transposed) ----
        #pragma unroll
        for (int i = 0; i < 8; ++i) {
            int v  = t + i * 256;
            int r  = v >> 5;
            int e0 = (v & 31) * 4;
            KV[(e0 + 0) * KTS + r] = kreg[i].x;
            KV[(e0 + 1) * KTS + r] = kreg[i].y;
            KV[(e0 + 2) * KTS + r] = kreg[i].z;
            KV[(e0 + 3) * KTS + r] = kreg[i].w;
        }
        __syncthreads();   // KT (and first-iter QT) ready

        // ---- GEMM1: s[2][4] = (Q/sqrtE) . K^T ----
        float s[2][4] = {};
        #pragma unroll 8
        for (int e = 0; e < 128; ++e) {
            float2 qv = *(const float2*)&QT[e * QTS + q0];
            float4 kv = *(const float4*)&KV[e * KTS + k0];
            s[0][0] = fmaf(qv.x, kv.x, s[0][0]);
            s[0][1] = fmaf(qv.x, kv.y, s[0][1]);
            s[0][2] = fmaf(qv.x, kv.z, s[0][2]);
            s[0][3] = fmaf(qv.x, kv.w, s[0][3]);
            s[1][0] = fmaf(qv.y, kv.x, s[1][0]);
            s[1][1] = fmaf(qv.y, kv.y, s[1][1]);
            s[1][2] = fmaf(qv.y, kv.z, s[1][2]);
            s[1][3] = fmaf(qv.y, kv.w, s[1][3]);
        }

        // ---- online softmax (reduce across 16 tk-lanes) ----
        float mnew[2];
        mnew[0] = fmaxf(fmaxf(s[0][0], s[0][1]), fmaxf(s[0][2], s[0][3]));
        mnew[1] = fmaxf(fmaxf(s[1][0], s[1][1]), fmaxf(s[1][2], s[1][3]));
        #pragma unroll
        for (int off = 1; off < 16; off <<= 1) {
            mnew[0] = fmaxf(mnew[0], __shfl_xor(mnew[0], off));
            mnew[1] = fmaxf(mnew[1], __shfl_xor(mnew[1], off));
        }
        float p[2][4], al[2], rs[2];
        #pragma unroll
        for (int i = 0; i < 2; ++i) {
            float mt = fmaxf(m[i], mnew[i]);
            al[i] = __expf(m[i] - mt);       // exp(-inf)=0 on first tile
            m[i]  = mt;
            p[i][0] = __expf(s[i][0] - mt);
            p[i][1] = __expf(s[i][1] - mt);
            p[i][2] = __expf(s[i][2] - mt);
            p[i][3] = __expf(s[i][3] - mt);
            rs[i] = (p[i][0] + p[i][1]) + (p[i][2] + p[i][3]);
        }
        #pragma unroll
        for (int off = 1; off < 16; off <<= 1) {
            rs[0] += __shfl_xor(rs[0], off);
            rs[1] += __shfl_xor(rs[1], off);
        }
        l[0] = l[0] * al[0] + rs[0];
        l[1] = l[1] * al[1] + rs[1];
        #pragma unroll
        for (int j = 0; j < 8; ++j) {
            O[0][j] *= al[0];
            O[1][j] *= al[1];
        }

        __syncthreads();   // everyone done reading KT

        // ---- write V (row-major) into shared region + PT ----
        #pragma unroll
        for (int i = 0; i < 8; ++i) {
            int v  = t + i * 256;
            int r  = v >> 5;
            int e0 = (v & 31) * 4;
            *(float4*)&KV[r * VTS + e0] = vreg[i];
        }
        #pragma unroll
        for (int j = 0; j < 4; ++j) {
            *(float2*)&PT[(k0 + j) * PTS + q0] = make_float2(p[0][j], p[1][j]);
        }
        __syncthreads();   // V, PT ready

        // ---- GEMM2: O += P . V ----
        #pragma unroll 8
        for (int k = 0; k < 64; ++k) {
            float2 pv = *(const float2*)&PT[k * PTS + q0];
            float4 v0 = *(const float4*)&KV[k * VTS + d0];
            float4 v1 = *(const float4*)&KV[k * VTS + d0 + 4];
            O[0][0] = fmaf(pv.x, v0.x, O[0][0]);
            O[0][1] = fmaf(pv.x, v0.y, O[0][1]);
            O[0][2] = fmaf(pv.x, v0.z, O[0][2]);
            O[0][3] = fmaf(pv.x, v0.w, O[0][3]);
            O[0][4] = fmaf(pv.x, v1.x, O[0][4]);
            O[0][5] = fmaf(pv.x, v1.y, O[0][5]);
            O[0][6] = fmaf(pv.x, v1.z, O[0][6]);
            O[0][7] = fmaf(pv.x, v1.w, O[0][7]);
            O[1][0] = fmaf(pv.y, v0.x, O[1][0]);
            O[1][1] = fmaf(pv.y, v0.y, O[1][1]);
            O[1][2] = fmaf(pv.y, v0.z, O[1][2]);
            O[1][3] = fmaf(pv.y, v0.w, O[1][3]);
            O[1][4] = fmaf(pv.y, v1.x, O[1][4]);
            O[1][5] = fmaf(pv.y, v1.y, O[1][5]);
            O[1][6] = fmaf(pv.y, v1.z, O[1][6]);
            O[1][7] = fmaf(pv.y, v1.w, O[1][7]);
        }
    }

    // ---- epilogue: divide by l, store ----
    #pragma unroll
    for (int i = 0; i < 2; ++i) {
        float inv = 1.0f / l[i];
        float4 r0v, r1v;
        r0v.x = O[i][0] * inv; r0v.y = O[i][1] * inv;
        r0v.z = O[i][2] * inv; r0v.w = O[i][3] * inv;
        r1v.x = O[i][4] * inv; r1v.y = O[i][5] * inv;
        r1v.z = O[i][6] * inv; r1v.w = O[i][7] * inv;
        size_t obase = (size_t)(qrow0 + q0 + i) * NE + d0;
        *(float4*)&outp[obase]     = r0v;
        *(float4*)&outp[obase + 4] = r1v;
    }
}

// ---------------------------------------------------------------------------
extern "C" void kernel_launch(void* const* d_in, const int* in_sizes, int n_in,
                              void* d_out, int out_size, void* d_ws, size_t ws_size,
                              hipStream_t stream)
{
    const float* x  = (const float*)d_in[0];
    const float* Wq = (const float*)d_in[1];
    const float* bq = (const float*)d_in[2];
    const float* Wk = (const float*)d_in[3];
    const float* bk = (const float*)d_in[4];
    const float* Wv = (const float*)d_in[5];
    const float* bv = (const float*)d_in[6];
    float* out = (float*)d_out;
    float* qkv = (float*)d_ws;   // needs 3*NROWS*NE*4 = 25.2 MB

    dim3 g1(NROWS / 32, 3, 2);
    qkv_kernel<<<g1, 256, 0, stream>>>(x, Wq, bq, Wk, bk, Wv, bv, qkv);

    dim3 g2(NS / 32, NB);
    attn_kernel<<<g2, 256, 0, stream>>>(qkv, out);
}

// Round 2
// 1370.414 us; speedup vs baseline: 1.4364x; 1.4364x over previous
//
#include <hip/hip_runtime.h>
#include <math.h>

#define NB 2
#define NS 8192
#define NE 128
#define NROWS (NB * NS)
#define RS 132   // padded LDS row stride (floats): 128 + 4 -> chunk stride 33 (odd mod 8)
#define PS 68    // P row stride (floats)

// ---------------------------------------------------------------------------
// QKV projection, dot-product form: out[r][o] = sum_e x[r][e] W[o][e] + b[o]
// grid (NROWS/32, 3, 2), block 256. Block: 32 rows x 64 o-cols of one matrix.
// Thread (tq,tk): rows {2tq,2tq+1}, o in {tk+16j}.
// ---------------------------------------------------------------------------
__global__ __launch_bounds__(256, 2)
void qkv_kernel(const float* __restrict__ x,
                const float* __restrict__ Wq, const float* __restrict__ bq,
                const float* __restrict__ Wk, const float* __restrict__ bk,
                const float* __restrict__ Wv, const float* __restrict__ bv,
                float* __restrict__ qkv)
{
    __shared__ float xL[32 * RS];
    __shared__ float wL[64 * RS];

    const int t    = threadIdx.x;
    const int row0 = blockIdx.x * 32;
    const int mat  = blockIdx.y;       // 0=Q 1=K 2=V
    const int oh   = blockIdx.z * 64;

    const float* W    = (mat == 0) ? Wq : (mat == 1) ? Wk : Wv;
    const float* bias = (mat == 0) ? bq : (mat == 1) ? bk : bv;
    float* out = qkv + (size_t)mat * NROWS * NE;

    // Stage x rows (row-major, padded): consecutive-chunk b128 writes, no conflicts
    #pragma unroll
    for (int i = 0; i < 4; ++i) {
        int v = t + i * 256;
        int r = v >> 5, c = v & 31;
        *(float4*)&xL[r * RS + c * 4] =
            *(const float4*)&x[(size_t)(row0 + r) * NE + c * 4];
    }
    // Stage W rows oh..oh+63
    #pragma unroll
    for (int i = 0; i < 8; ++i) {
        int v = t + i * 256;
        int r = v >> 5, c = v & 31;
        *(float4*)&wL[r * RS + c * 4] =
            *(const float4*)&W[(size_t)(oh + r) * NE + c * 4];
    }
    __syncthreads();

    const int tq = t >> 4, tk = t & 15;
    const int r0 = 2 * tq;

    float acc[2][4] = {};
    #pragma unroll 4
    for (int c = 0; c < 32; ++c) {
        float4 xa = *(const float4*)&xL[r0 * RS + c * 4];
        float4 xb = *(const float4*)&xL[(r0 + 1) * RS + c * 4];
        #pragma unroll
        for (int j = 0; j < 4; ++j) {
            float4 w4 = *(const float4*)&wL[(tk + 16 * j) * RS + c * 4];
            acc[0][j] = fmaf(xa.x, w4.x, fmaf(xa.y, w4.y,
                        fmaf(xa.z, w4.z, fmaf(xa.w, w4.w, acc[0][j]))));
            acc[1][j] = fmaf(xb.x, w4.x, fmaf(xb.y, w4.y,
                        fmaf(xb.z, w4.z, fmaf(xb.w, w4.w, acc[1][j]))));
        }
    }

    #pragma unroll
    for (int i = 0; i < 2; ++i) {
        #pragma unroll
        for (int j = 0; j < 4; ++j) {
            int o = tk + 16 * j;
            out[(size_t)(row0 + r0 + i) * NE + oh + o] = acc[i][j] + bias[oh + o];
        }
    }
}

// ---------------------------------------------------------------------------
// Flash attention, fp32, conflict-free LDS. grid (NS/32, NB), block 256.
// LDS: qL 16896 + kvL 33792 (K then V, time-shared) + pL 8704 = 59392 B
//   -> 2 blocks/CU, 8 waves/CU.
// ---------------------------------------------------------------------------
__global__ __launch_bounds__(256, 2)
void attn_kernel(const float* __restrict__ qkv, float* __restrict__ outp)
{
    __shared__ float qL[32 * RS];   // Q rows, pre-scaled by 1/sqrt(E)
    __shared__ float kvL[64 * RS];  // K rows OR V rows (time-shared)
    __shared__ float pL[32 * PS];   // P[q][k]

    const int t  = threadIdx.x;
    const int qt = blockIdx.x;
    const int b  = blockIdx.y;

    const float* Q = qkv;
    const float* K = qkv + (size_t)NROWS * NE;
    const float* V = qkv + (size_t)2 * NROWS * NE;

    const int qrow0 = b * NS + qt * 32;
    const float sc = 0.08838834764831845f;   // 1/sqrt(128)

    #pragma unroll
    for (int i = 0; i < 4; ++i) {
        int v = t + i * 256;
        int r = v >> 5, c = v & 31;
        float4 q4 = *(const float4*)&Q[(size_t)(qrow0 + r) * NE + c * 4];
        q4.x *= sc; q4.y *= sc; q4.z *= sc; q4.w *= sc;
        *(float4*)&qL[r * RS + c * 4] = q4;
    }

    const int tq = t >> 4, tk = t & 15;
    const int q0 = 2 * tq;

    float m[2] = {-INFINITY, -INFINITY};
    float l[2] = {0.f, 0.f};
    float O[2][8] = {};

    for (int kt = 0; kt < NS / 64; ++kt) {
        const size_t kbase = ((size_t)b * NS + kt * 64) * NE;

        __syncthreads();   // prev GEMM2 done with kvL/pL (covers qL staging on iter 0)

        // ---- stage K tile row-major (conflict-free b128 writes) ----
        #pragma unroll
        for (int i = 0; i < 8; ++i) {
            int v = t + i * 256;
            int r = v >> 5, c = v & 31;
            *(float4*)&kvL[r * RS + c * 4] =
                *(const float4*)&K[kbase + (size_t)r * NE + c * 4];
        }
        __syncthreads();   // K (and Q) ready

        // ---- GEMM1: s[i][j] = Qs[q0+i] . K[tk+16j] ----
        float s[2][4] = {};
        #pragma unroll 4
        for (int c = 0; c < 32; ++c) {
            float4 qa = *(const float4*)&qL[q0 * RS + c * 4];
            float4 qb = *(const float4*)&qL[(q0 + 1) * RS + c * 4];
            #pragma unroll
            for (int j = 0; j < 4; ++j) {
                float4 k4 = *(const float4*)&kvL[(tk + 16 * j) * RS + c * 4];
                s[0][j] = fmaf(qa.x, k4.x, fmaf(qa.y, k4.y,
                          fmaf(qa.z, k4.z, fmaf(qa.w, k4.w, s[0][j]))));
                s[1][j] = fmaf(qb.x, k4.x, fmaf(qb.y, k4.y,
                          fmaf(qb.z, k4.z, fmaf(qb.w, k4.w, s[1][j]))));
            }
        }

        // ---- online softmax (reduce across the 16 tk lanes) ----
        float mnew[2];
        mnew[0] = fmaxf(fmaxf(s[0][0], s[0][1]), fmaxf(s[0][2], s[0][3]));
        mnew[1] = fmaxf(fmaxf(s[1][0], s[1][1]), fmaxf(s[1][2], s[1][3]));
        #pragma unroll
        for (int off = 1; off < 16; off <<= 1) {
            mnew[0] = fmaxf(mnew[0], __shfl_xor(mnew[0], off));
            mnew[1] = fmaxf(mnew[1], __shfl_xor(mnew[1], off));
        }
        float p[2][4], al[2], rs[2];
        #pragma unroll
        for (int i = 0; i < 2; ++i) {
            float mt = fmaxf(m[i], mnew[i]);
            al[i] = __expf(m[i] - mt);       // exp(-inf)=0 on first tile
            m[i]  = mt;
            p[i][0] = __expf(s[i][0] - mt);
            p[i][1] = __expf(s[i][1] - mt);
            p[i][2] = __expf(s[i][2] - mt);
            p[i][3] = __expf(s[i][3] - mt);
            rs[i] = (p[i][0] + p[i][1]) + (p[i][2] + p[i][3]);
        }
        #pragma unroll
        for (int off = 1; off < 16; off <<= 1) {
            rs[0] += __shfl_xor(rs[0], off);
            rs[1] += __shfl_xor(rs[1], off);
        }
        l[0] = l[0] * al[0] + rs[0];
        l[1] = l[1] * al[1] + rs[1];
        #pragma unroll
        for (int j = 0; j < 8; ++j) {
            O[0][j] *= al[0];
            O[1][j] *= al[1];
        }

        __syncthreads();   // everyone done reading K

        // ---- stage V tile row-major into same region; write P ----
        #pragma unroll
        for (int i = 0; i < 8; ++i) {
            int v = t + i * 256;
            int r = v >> 5, c = v & 31;
            *(float4*)&kvL[r * RS + c * 4] =
                *(const float4*)&V[kbase + (size_t)r * NE + c * 4];
        }
        #pragma unroll
        for (int i = 0; i < 2; ++i) {
            #pragma unroll
            for (int j = 0; j < 4; ++j) {
                pL[(q0 + i) * PS + tk + 16 * j] = p[i][j];   // 2-way max: free
            }
        }
        __syncthreads();   // V, P ready

        // ---- GEMM2: O[i][d] += P[q0+i][k] * V[k][d], d in {4tk.., 64+4tk..} ----
        #pragma unroll 4
        for (int k = 0; k < 64; k += 2) {
            float2 pa = *(const float2*)&pL[q0 * PS + k];
            float2 pb = *(const float2*)&pL[(q0 + 1) * PS + k];
            float4 v00 = *(const float4*)&kvL[k * RS + 4 * tk];
            float4 v01 = *(const float4*)&kvL[k * RS + 64 + 4 * tk];
            float4 v10 = *(const float4*)&kvL[(k + 1) * RS + 4 * tk];
            float4 v11 = *(const float4*)&kvL[(k + 1) * RS + 64 + 4 * tk];

            O[0][0] = fmaf(pa.x, v00.x, O[0][0]);
            O[0][1] = fmaf(pa.x, v00.y, O[0][1]);
            O[0][2] = fmaf(pa.x, v00.z, O[0][2]);
            O[0][3] = fmaf(pa.x, v00.w, O[0][3]);
            O[0][4] = fmaf(pa.x, v01.x, O[0][4]);
            O[0][5] = fmaf(pa.x, v01.y, O[0][5]);
            O[0][6] = fmaf(pa.x, v01.z, O[0][6]);
            O[0][7] = fmaf(pa.x, v01.w, O[0][7]);
            O[1][0] = fmaf(pb.x, v00.x, O[1][0]);
            O[1][1] = fmaf(pb.x, v00.y, O[1][1]);
            O[1][2] = fmaf(pb.x, v00.z, O[1][2]);
            O[1][3] = fmaf(pb.x, v00.w, O[1][3]);
            O[1][4] = fmaf(pb.x, v01.x, O[1][4]);
            O[1][5] = fmaf(pb.x, v01.y, O[1][5]);
            O[1][6] = fmaf(pb.x, v01.z, O[1][6]);
            O[1][7] = fmaf(pb.x, v01.w, O[1][7]);

            O[0][0] = fmaf(pa.y, v10.x, O[0][0]);
            O[0][1] = fmaf(pa.y, v10.y, O[0][1]);
            O[0][2] = fmaf(pa.y, v10.z, O[0][2]);
            O[0][3] = fmaf(pa.y, v10.w, O[0][3]);
            O[0][4] = fmaf(pa.y, v11.x, O[0][4]);
            O[0][5] = fmaf(pa.y, v11.y, O[0][5]);
            O[0][6] = fmaf(pa.y, v11.z, O[0][6]);
            O[0][7] = fmaf(pa.y, v11.w, O[0][7]);
            O[1][0] = fmaf(pb.y, v10.x, O[1][0]);
            O[1][1] = fmaf(pb.y, v10.y, O[1][1]);
            O[1][2] = fmaf(pb.y, v10.z, O[1][2]);
            O[1][3] = fmaf(pb.y, v10.w, O[1][3]);
            O[1][4] = fmaf(pb.y, v11.x, O[1][4]);
            O[1][5] = fmaf(pb.y, v11.y, O[1][5]);
            O[1][6] = fmaf(pb.y, v11.z, O[1][6]);
            O[1][7] = fmaf(pb.y, v11.w, O[1][7]);
        }
    }

    // ---- epilogue ----
    #pragma unroll
    for (int i = 0; i < 2; ++i) {
        float inv = 1.0f / l[i];
        float4 r0v, r1v;
        r0v.x = O[i][0] * inv; r0v.y = O[i][1] * inv;
        r0v.z = O[i][2] * inv; r0v.w = O[i][3] * inv;
        r1v.x = O[i][4] * inv; r1v.y = O[i][5] * inv;
        r1v.z = O[i][6] * inv; r1v.w = O[i][7] * inv;
        size_t ob = (size_t)(qrow0 + q0 + i) * NE;
        *(float4*)&outp[ob + 4 * tk]      = r0v;
        *(float4*)&outp[ob + 64 + 4 * tk] = r1v;
    }
}

// ---------------------------------------------------------------------------
extern "C" void kernel_launch(void* const* d_in, const int* in_sizes, int n_in,
                              void* d_out, int out_size, void* d_ws, size_t ws_size,
                              hipStream_t stream)
{
    const float* x  = (const float*)d_in[0];
    const float* Wq = (const float*)d_in[1];
    const float* bq = (const float*)d_in[2];
    const float* Wk = (const float*)d_in[3];
    const float* bk = (const float*)d_in[4];
    const float* Wv = (const float*)d_in[5];
    const float* bv = (const float*)d_in[6];
    float* out = (float*)d_out;
    float* qkv = (float*)d_ws;   // 3*NROWS*NE*4 = 25.2 MB

    dim3 g1(NROWS / 32, 3, 2);
    qkv_kernel<<<g1, 256, 0, stream>>>(x, Wq, bq, Wk, bk, Wv, bv, qkv);

    dim3 g2(NS / 32, NB);
    attn_kernel<<<g2, 256, 0, stream>>>(qkv, out);
}

// Round 5
// 414.100 us; speedup vs baseline: 4.7537x; 3.3094x over previous
//
#include <hip/hip_runtime.h>
#include <math.h>

#define NB 2
#define NS 8192
#define NE 128
#define NROWS (NB * NS)
#define RS 132   // qkv_kernel fp32 LDS row stride

typedef __attribute__((ext_vector_type(8))) short s8v;    // 8 bf16 (4 VGPR) MFMA frag
typedef __attribute__((ext_vector_type(16))) float fx16;  // 32x32 accumulator

static __device__ __forceinline__ unsigned short f2bf(float x) {
    unsigned int u = __float_as_uint(x);
    u += 0x7FFFu + ((u >> 16) & 1u);          // RNE (finite inputs only)
    return (unsigned short)(u >> 16);
}
static __device__ __forceinline__ unsigned int pkbf(float a, float b) {
    unsigned int ua = __float_as_uint(a), ub = __float_as_uint(b);
    ua += 0x7FFFu + ((ua >> 16) & 1u);
    ub += 0x7FFFu + ((ub >> 16) & 1u);
    return (ua >> 16) | (ub & 0xFFFF0000u);   // [a_bf16 | b_bf16<<16]
}

// ---------------------------------------------------------------------------
// QKV projection in fp32 (exact), output bf16. grid (NROWS/32, 3, 2), block 256.
// ---------------------------------------------------------------------------
__global__ __launch_bounds__(256, 2)
void qkv_kernel(const float* __restrict__ x,
                const float* __restrict__ Wq, const float* __restrict__ bq,
                const float* __restrict__ Wk, const float* __restrict__ bk,
                const float* __restrict__ Wv, const float* __restrict__ bv,
                unsigned short* __restrict__ qkv)
{
    __shared__ float xL[32 * RS];
    __shared__ float wL[64 * RS];

    const int t    = threadIdx.x;
    const int row0 = blockIdx.x * 32;
    const int mat  = blockIdx.y;
    const int oh   = blockIdx.z * 64;

    const float* W    = (mat == 0) ? Wq : (mat == 1) ? Wk : Wv;
    const float* bias = (mat == 0) ? bq : (mat == 1) ? bk : bv;
    unsigned short* out = qkv + (size_t)mat * NROWS * NE;

    #pragma unroll
    for (int i = 0; i < 4; ++i) {
        int v = t + i * 256;
        int r = v >> 5, c = v & 31;
        *(float4*)&xL[r * RS + c * 4] =
            *(const float4*)&x[(size_t)(row0 + r) * NE + c * 4];
    }
    #pragma unroll
    for (int i = 0; i < 8; ++i) {
        int v = t + i * 256;
        int r = v >> 5, c = v & 31;
        *(float4*)&wL[r * RS + c * 4] =
            *(const float4*)&W[(size_t)(oh + r) * NE + c * 4];
    }
    __syncthreads();

    const int tq = t >> 4, tk = t & 15;
    const int r0 = 2 * tq;

    float acc[2][4] = {};
    #pragma unroll 4
    for (int c = 0; c < 32; ++c) {
        float4 xa = *(const float4*)&xL[r0 * RS + c * 4];
        float4 xb = *(const float4*)&xL[(r0 + 1) * RS + c * 4];
        #pragma unroll
        for (int j = 0; j < 4; ++j) {
            float4 w4 = *(const float4*)&wL[(tk + 16 * j) * RS + c * 4];
            acc[0][j] = fmaf(xa.x, w4.x, fmaf(xa.y, w4.y,
                        fmaf(xa.z, w4.z, fmaf(xa.w, w4.w, acc[0][j]))));
            acc[1][j] = fmaf(xb.x, w4.x, fmaf(xb.y, w4.y,
                        fmaf(xb.z, w4.z, fmaf(xb.w, w4.w, acc[1][j]))));
        }
    }

    #pragma unroll
    for (int i = 0; i < 2; ++i)
        #pragma unroll
        for (int j = 0; j < 4; ++j) {
            int o = tk + 16 * j;
            out[(size_t)(row0 + r0 + i) * NE + oh + o] = f2bf(acc[i][j] + bias[oh + o]);
        }
}

// ---------------------------------------------------------------------------
// bf16 MFMA flash attention. grid 256, block 256 (4 waves).
// Wave w: q-group g=w>>1 (32 rows), k-split ks=w&1 (even/odd 64-key tiles).
// S^T = K·Q^T (per-lane softmax), P via register exchange, V^T staged in LDS.
// ---------------------------------------------------------------------------
__global__ __launch_bounds__(256, 1)
void attn_kernel(const unsigned short* __restrict__ qkv, float* __restrict__ outp)
{
    __shared__ unsigned int vbuf[2][128 * 36];   // 36864 B; reused for merge

    const int t  = threadIdx.x;
    const int id = blockIdx.x;
    const int b  = (id >> 2) & 1;                 // XCD 0-3 -> batch 0, 4-7 -> batch 1
    const int qt = ((id >> 3) << 2) | (id & 3);   // 0..127

    const unsigned short* Qg = qkv;
    const unsigned short* Kg = qkv + (size_t)NROWS * NE;
    const unsigned short* Vg = qkv + (size_t)2 * NROWS * NE;

    const int w = t >> 6, lane = t & 63, lq = lane & 31, h = lane >> 5;
    const int g = w >> 1, ks = w & 1;

    const int qbase = b * NS + qt * 64 + g * 32;
    const size_t kvbatch = (size_t)b * NS * NE;

    // Q fragments (B-operand: n=lane&31=q, kk=(lane>>5)*8+j), direct from global
    s8v qf[8];
    #pragma unroll
    for (int s = 0; s < 8; ++s)
        qf[s] = *(const s8v*)(Qg + (size_t)(qbase + lq) * NE + s * 16 + h * 8);

    fx16 acc[4];
    #pragma unroll
    for (int dt = 0; dt < 4; ++dt)
        #pragma unroll
        for (int i = 0; i < 16; ++i) acc[dt][i] = 0.f;

    float m2 = -INFINITY, l = 0.f;
    const float C1 = 0.12751743f;   // log2(e)/sqrt(128)

    for (int r = 0; r < 64; ++r) {
        __syncthreads();   // prev round done reading vbuf

        // ---- stage V tiles 2r (buf0), 2r+1 (buf1) as vT[d][key-pair packed] ----
        #pragma unroll
        for (int i = 0; i < 4; ++i) {
            int v = t + i * 256;                 // 1024 units: 2keys x 8d each
            int buf = v >> 9, u = v & 511;
            int kp = u & 31, dg = u >> 5;
            const unsigned short* p0 =
                Vg + kvbatch + (size_t)((2 * r + buf) * 64 + 2 * kp) * NE + dg * 8;
            union { uint4 q; unsigned short s[8]; } a, c;
            a.q = *(const uint4*)p0;
            c.q = *(const uint4*)(p0 + NE);
            #pragma unroll
            for (int e = 0; e < 8; ++e)
                vbuf[buf][(dg * 8 + e) * 36 + kp] =
                    (unsigned int)a.s[e] | ((unsigned int)c.s[e] << 16);
        }
        __syncthreads();   // V ready

        const int kt = 2 * r + ks;

        // ---- GEMM1: S^T[key][q] = K·Q^T, two 32-key m-tiles ----
        fx16 st[2];
        #pragma unroll
        for (int mt = 0; mt < 2; ++mt)
            #pragma unroll
            for (int i = 0; i < 16; ++i) st[mt][i] = 0.f;

        const unsigned short* Kt = Kg + kvbatch + (size_t)(kt * 64) * NE;
        #pragma unroll
        for (int mt = 0; mt < 2; ++mt) {
            const unsigned short* Kr = Kt + (size_t)(mt * 32 + lq) * NE + h * 8;
            #pragma unroll
            for (int s = 0; s < 8; ++s) {
                s8v af = *(const s8v*)(Kr + s * 16);
                st[mt] = __builtin_amdgcn_mfma_f32_32x32x16_bf16(af, qf[s], st[mt], 0, 0, 0);
            }
        }

        // ---- per-lane online softmax (lane owns q=lane&31, 32 keys) ----
        float pex[32];
        #pragma unroll
        for (int mt = 0; mt < 2; ++mt)
            #pragma unroll
            for (int rg = 0; rg < 16; ++rg) pex[mt * 16 + rg] = st[mt][rg] * C1;

        float mn = pex[0];
        #pragma unroll
        for (int i = 1; i < 32; ++i) mn = fmaxf(mn, pex[i]);
        mn = fmaxf(mn, __shfl_xor(mn, 32));
        float m2n = fmaxf(m2, mn);
        float alpha = exp2f(m2 - m2n);
        m2 = m2n;

        float lsum = 0.f;
        #pragma unroll
        for (int i = 0; i < 32; ++i) {
            pex[i] = exp2f(pex[i] - m2n);
            lsum += pex[i];
        }
        lsum += __shfl_xor(lsum, 32);
        l = l * alpha + lsum;

        // ---- O rescale: alpha per q-ROW (C-layout rows), broadcast by shfl ----
        float av[16];
        #pragma unroll
        for (int rg = 0; rg < 16; ++rg) {
            int rowv = (rg & 3) + 8 * (rg >> 2) + 4 * h;
            av[rg] = __shfl(alpha, rowv);
        }
        #pragma unroll
        for (int dt = 0; dt < 4; ++dt)
            #pragma unroll
            for (int rg = 0; rg < 16; ++rg) acc[dt][rg] *= av[rg];

        // ---- GEMM2: O[q][d] += P·V, P via register half-exchange ----
        #pragma unroll
        for (int s2 = 0; s2 < 4; ++s2) {
            unsigned int P0 = pkbf(pex[s2 * 8 + 0], pex[s2 * 8 + 1]);
            unsigned int P1 = pkbf(pex[s2 * 8 + 2], pex[s2 * 8 + 3]);
            unsigned int P2 = pkbf(pex[s2 * 8 + 4], pex[s2 * 8 + 5]);
            unsigned int P3 = pkbf(pex[s2 * 8 + 6], pex[s2 * 8 + 7]);
            unsigned int X0 = (unsigned int)__shfl_xor((int)P0, 32);
            unsigned int X1 = (unsigned int)__shfl_xor((int)P1, 32);
            unsigned int X2 = (unsigned int)__shfl_xor((int)P2, 32);
            unsigned int X3 = (unsigned int)__shfl_xor((int)P3, 32);
            union { unsigned int u[4]; s8v v; } pf;
            pf.u[0] = h ? X2 : P0;
            pf.u[1] = h ? X3 : P1;
            pf.u[2] = h ? P2 : X0;
            pf.u[3] = h ? P3 : X1;
            #pragma unroll
            for (int dt = 0; dt < 4; ++dt) {
                s8v vf = *(const s8v*)&vbuf[ks][(lq + 32 * dt) * 36 + s2 * 8 + h * 4];
                acc[dt] = __builtin_amdgcn_mfma_f32_32x32x16_bf16(pf.v, vf, acc[dt], 0, 0, 0);
            }
        }
    }

    // ---- merge k-split pairs (waves g*2 and g*2+1) through LDS ----
    __syncthreads();
    float* OB = (float*)&vbuf[0][0];         // 2 groups x 32x128 fp32 = 32768 B
    float* ML = OB + 2 * 32 * 128;           // 2 groups x (m[32], l[32])

    if (ks == 1) {
        #pragma unroll
        for (int dt = 0; dt < 4; ++dt)
            #pragma unroll
            for (int rg = 0; rg < 16; ++rg) {
                int row = (rg & 3) + 8 * (rg >> 2) + 4 * h;
                OB[g * 4096 + row * 128 + lq + 32 * dt] = acc[dt][rg];
            }
        if (lane < 32) { ML[g * 64 + lq] = m2; ML[g * 64 + 32 + lq] = l; }
    }
    __syncthreads();
    if (ks == 0) {
        float m2B = ML[g * 64 + lq], lB = ML[g * 64 + 32 + lq];
        float mF = fmaxf(m2, m2B);
        float aA = exp2f(m2 - mF), aB = exp2f(m2B - mF);
        float inv = 1.f / (l * aA + lB * aB);
        float sA = aA * inv, sB = aB * inv;
        float rA[16], rB[16];
        #pragma unroll
        for (int rg = 0; rg < 16; ++rg) {
            int rowv = (rg & 3) + 8 * (rg >> 2) + 4 * h;
            rA[rg] = __shfl(sA, rowv);
            rB[rg] = __shfl(sB, rowv);
        }
        #pragma unroll
        for (int dt = 0; dt < 4; ++dt)
            #pragma unroll
            for (int rg = 0; rg < 16; ++rg) {
                int row = (rg & 3) + 8 * (rg >> 2) + 4 * h;
                float vO = acc[dt][rg] * rA[rg] +
                           OB[g * 4096 + row * 128 + lq + 32 * dt] * rB[rg];
                outp[(size_t)(qbase + row) * NE + lq + 32 * dt] = vO;
            }
    }
}

// ---------------------------------------------------------------------------
extern "C" void kernel_launch(void* const* d_in, const int* in_sizes, int n_in,
                              void* d_out, int out_size, void* d_ws, size_t ws_size,
                              hipStream_t stream)
{
    const float* x  = (const float*)d_in[0];
    const float* Wq = (const float*)d_in[1];
    const float* bq = (const float*)d_in[2];
    const float* Wk = (const float*)d_in[3];
    const float* bk = (const float*)d_in[4];
    const float* Wv = (const float*)d_in[5];
    const float* bv = (const float*)d_in[6];
    float* out = (float*)d_out;
    unsigned short* qkv = (unsigned short*)d_ws;   // 3*NROWS*NE*2 = 12.6 MB

    dim3 g1(NROWS / 32, 3, 2);
    qkv_kernel<<<g1, 256, 0, stream>>>(x, Wq, bq, Wk, bk, Wv, bv, qkv);

    attn_kernel<<<256, 256, 0, stream>>>(qkv, out);
}

// Round 6
// 266.487 us; speedup vs baseline: 7.3868x; 1.5539x over previous
//
#include <hip/hip_runtime.h>
#include <math.h>

#define NB 2
#define NS 8192
#define NE 128
#define NROWS (NB * NS)
#define RS 132   // qkv_kernel fp32 LDS row stride

typedef __attribute__((ext_vector_type(8))) short s8v;    // 8 bf16 (4 VGPR) MFMA frag
typedef __attribute__((ext_vector_type(16))) float fx16;  // 32x32 accumulator

static __device__ __forceinline__ unsigned short f2bf(float x) {
    unsigned int u = __float_as_uint(x);
    u += 0x7FFFu + ((u >> 16) & 1u);          // RNE (finite inputs only)
    return (unsigned short)(u >> 16);
}
static __device__ __forceinline__ unsigned int pkbf(float a, float b) {
    unsigned int ua = __float_as_uint(a), ub = __float_as_uint(b);
    ua += 0x7FFFu + ((ua >> 16) & 1u);
    ub += 0x7FFFu + ((ub >> 16) & 1u);
    return (ua >> 16) | (ub & 0xFFFF0000u);   // [a_bf16 | b_bf16<<16]
}

// ---------------------------------------------------------------------------
// QKV projection fp32->bf16. Q pre-scaled by log2(e)/sqrt(E); V written
// TRANSPOSED as Vt[b][d][key] so attention stages it with zero ALU transform.
// grid (NROWS/32, 3, 2), block 256.
// ---------------------------------------------------------------------------
__global__ __launch_bounds__(256, 2)
void qkv_kernel(const float* __restrict__ x,
                const float* __restrict__ Wq, const float* __restrict__ bq,
                const float* __restrict__ Wk, const float* __restrict__ bk,
                const float* __restrict__ Wv, const float* __restrict__ bv,
                unsigned short* __restrict__ qkv)
{
    __shared__ float xL[32 * RS];
    __shared__ float wL[64 * RS];

    const int t    = threadIdx.x;
    const int row0 = blockIdx.x * 32;
    const int mat  = blockIdx.y;
    const int oh   = blockIdx.z * 64;

    const float* W    = (mat == 0) ? Wq : (mat == 1) ? Wk : Wv;
    const float* bias = (mat == 0) ? bq : (mat == 1) ? bk : bv;
    unsigned short* out = qkv + (size_t)mat * NROWS * NE;
    const float osc = (mat == 0) ? 0.12751743f : 1.0f;   // log2(e)/sqrt(128)

    #pragma unroll
    for (int i = 0; i < 4; ++i) {
        int v = t + i * 256;
        int r = v >> 5, c = v & 31;
        *(float4*)&xL[r * RS + c * 4] =
            *(const float4*)&x[(size_t)(row0 + r) * NE + c * 4];
    }
    #pragma unroll
    for (int i = 0; i < 8; ++i) {
        int v = t + i * 256;
        int r = v >> 5, c = v & 31;
        *(float4*)&wL[r * RS + c * 4] =
            *(const float4*)&W[(size_t)(oh + r) * NE + c * 4];
    }
    __syncthreads();

    const int tq = t >> 4, tk = t & 15;
    const int r0 = 2 * tq;

    float acc[2][4] = {};
    #pragma unroll 4
    for (int c = 0; c < 32; ++c) {
        float4 xa = *(const float4*)&xL[r0 * RS + c * 4];
        float4 xb = *(const float4*)&xL[(r0 + 1) * RS + c * 4];
        #pragma unroll
        for (int j = 0; j < 4; ++j) {
            float4 w4 = *(const float4*)&wL[(tk + 16 * j) * RS + c * 4];
            acc[0][j] = fmaf(xa.x, w4.x, fmaf(xa.y, w4.y,
                        fmaf(xa.z, w4.z, fmaf(xa.w, w4.w, acc[0][j]))));
            acc[1][j] = fmaf(xb.x, w4.x, fmaf(xb.y, w4.y,
                        fmaf(xb.z, w4.z, fmaf(xb.w, w4.w, acc[1][j]))));
        }
    }

    #pragma unroll
    for (int i = 0; i < 2; ++i)
        #pragma unroll
        for (int j = 0; j < 4; ++j) {
            int o = tk + 16 * j;
            float val = (acc[i][j] + bias[oh + o]) * osc;
            int grow = row0 + r0 + i;
            if (mat != 2) {
                out[(size_t)grow * NE + oh + o] = f2bf(val);
            } else {
                int bb = grow >> 13, key = grow & (NS - 1);   // NS = 2^13
                out[((size_t)(bb * NE + oh + o) << 13) + key] = f2bf(val);
            }
        }
}

// ---------------------------------------------------------------------------
// bf16 MFMA flash attention, barrier-free main loop. grid 512, block 256.
// Block = 32 q-rows; wave w owns keys [w*2048, (w+1)*2048), private LDS
// quarter for its V^T tile. 4-way online-softmax merge at the end.
// LDS 73728 B -> 2 blocks/CU = 8 waves/CU (2/SIMD).
// ---------------------------------------------------------------------------
__global__ __launch_bounds__(256, 2)
void attn_kernel(const unsigned short* __restrict__ qkv, float* __restrict__ outp)
{
    __shared__ unsigned short vsh[4][128][72];   // 73728 B; reused for merge

    const int t  = threadIdx.x;
    const int id = blockIdx.x;                    // 0..511
    const int b  = (id >> 2) & 1;                 // XCD 0-3 -> batch 0, 4-7 -> batch 1
    const int qt = ((id >> 3) << 2) | (id & 3);   // 0..255

    const unsigned short* Qg = qkv;
    const unsigned short* Kg = qkv + (size_t)NROWS * NE;
    const unsigned short* Vt = qkv + (size_t)2 * NROWS * NE;   // [b][d][key]

    const int w = t >> 6, lane = t & 63, lq = lane & 31, h = lane >> 5;
    const int qbase = b * NS + qt * 32;
    const size_t kvbatch = (size_t)b * NS * NE;
    const unsigned short* Vb = Vt + (size_t)b * NE * NS;

    // Q fragments (B-operand: n=lane&31=q, k=(lane>>5)*8+j) — pre-scaled in qkv
    s8v qf[8];
    #pragma unroll
    for (int s = 0; s < 8; ++s)
        qf[s] = *(const s8v*)(Qg + (size_t)(qbase + lq) * NE + s * 16 + h * 8);

    fx16 acc[4];
    #pragma unroll
    for (int dt = 0; dt < 4; ++dt)
        #pragma unroll
        for (int i = 0; i < 16; ++i) acc[dt][i] = 0.f;

    float m2 = -INFINITY, l = 0.f;
    const int k0w = w * 2048;

    for (int r = 0; r < 32; ++r) {
        const int key0 = k0w + r * 64;

        // ---- stage own V^T tile (128 d x 64 keys), coalesced, no barrier ----
        #pragma unroll
        for (int i = 0; i < 16; ++i) {
            int d  = i * 8 + (lane >> 3);
            int kk = (lane & 7) * 8;
            *(uint4*)&vsh[w][d][kk] =
                *(const uint4*)&Vb[((size_t)d << 13) + key0 + kk];
        }

        // ---- GEMM1: S^T = K·Q^T (K direct from global, L1/L2-resident) ----
        fx16 st[2];
        #pragma unroll
        for (int mt = 0; mt < 2; ++mt)
            #pragma unroll
            for (int i = 0; i < 16; ++i) st[mt][i] = 0.f;

        const unsigned short* Kt = Kg + kvbatch + (size_t)key0 * NE;
        #pragma unroll
        for (int mt = 0; mt < 2; ++mt) {
            const unsigned short* Kr = Kt + (size_t)(mt * 32 + lq) * NE + h * 8;
            #pragma unroll
            for (int s = 0; s < 8; ++s) {
                s8v af = *(const s8v*)(Kr + s * 16);
                st[mt] = __builtin_amdgcn_mfma_f32_32x32x16_bf16(af, qf[s], st[mt], 0, 0, 0);
            }
        }

        // ---- per-lane online softmax (scores already in log2 domain) ----
        float pex[32];
        #pragma unroll
        for (int mt = 0; mt < 2; ++mt)
            #pragma unroll
            for (int rg = 0; rg < 16; ++rg) pex[mt * 16 + rg] = st[mt][rg];

        float mn = pex[0];
        #pragma unroll
        for (int i = 1; i < 32; ++i) mn = fmaxf(mn, pex[i]);
        mn = fmaxf(mn, __shfl_xor(mn, 32));
        float m2n = fmaxf(m2, mn);
        float alpha = exp2f(m2 - m2n);
        m2 = m2n;

        float lsum = 0.f;
        #pragma unroll
        for (int i = 0; i < 32; ++i) {
            pex[i] = exp2f(pex[i] - m2n);
            lsum += pex[i];
        }
        lsum += __shfl_xor(lsum, 32);
        l = l * alpha + lsum;

        // ---- O rescale, skipped wave-uniformly when no max update ----
        if (__ballot(alpha != 1.0f)) {
            float av[16];
            #pragma unroll
            for (int rg = 0; rg < 16; ++rg) {
                int rowv = (rg & 3) + 8 * (rg >> 2) + 4 * h;
                av[rg] = __shfl(alpha, rowv);
            }
            #pragma unroll
            for (int dt = 0; dt < 4; ++dt)
                #pragma unroll
                for (int rg = 0; rg < 16; ++rg) acc[dt][rg] *= av[rg];
        }

        // ---- GEMM2: O += P·V, P via register half-exchange, V from own LDS ----
        #pragma unroll
        for (int s2 = 0; s2 < 4; ++s2) {
            unsigned int P0 = pkbf(pex[s2 * 8 + 0], pex[s2 * 8 + 1]);
            unsigned int P1 = pkbf(pex[s2 * 8 + 2], pex[s2 * 8 + 3]);
            unsigned int P2 = pkbf(pex[s2 * 8 + 4], pex[s2 * 8 + 5]);
            unsigned int P3 = pkbf(pex[s2 * 8 + 6], pex[s2 * 8 + 7]);
            unsigned int X0 = (unsigned int)__shfl_xor((int)P0, 32);
            unsigned int X1 = (unsigned int)__shfl_xor((int)P1, 32);
            unsigned int X2 = (unsigned int)__shfl_xor((int)P2, 32);
            unsigned int X3 = (unsigned int)__shfl_xor((int)P3, 32);
            union { unsigned int u[4]; s8v v; } pf;
            pf.u[0] = h ? X2 : P0;
            pf.u[1] = h ? X3 : P1;
            pf.u[2] = h ? P2 : X0;
            pf.u[3] = h ? P3 : X1;
            #pragma unroll
            for (int dt = 0; dt < 4; ++dt) {
                s8v vf = *(const s8v*)&vsh[w][lq + 32 * dt][s2 * 16 + h * 8];
                acc[dt] = __builtin_amdgcn_mfma_f32_32x32x16_bf16(pf.v, vf, acc[dt], 0, 0, 0);
            }
        }
    }

    // ---- 4-way merge across waves (the only barriers in the kernel) ----
    __syncthreads();
    float* OB = (float*)&vsh[0][0][0];       // 3 x 32x128 fp32 = 48 KiB
    float* ML = OB + 3 * 4096;               // 3 x (m[32], l[32])

    if (w > 0) {
        #pragma unroll
        for (int dt = 0; dt < 4; ++dt)
            #pragma unroll
            for (int rg = 0; rg < 16; ++rg) {
                int row = (rg & 3) + 8 * (rg >> 2) + 4 * h;
                OB[(w - 1) * 4096 + row * 128 + lq + 32 * dt] = acc[dt][rg];
            }
        if (lane < 32) { ML[(w - 1) * 64 + lq] = m2; ML[(w - 1) * 64 + 32 + lq] = l; }
    }
    __syncthreads();
    if (w == 0) {
        float mj0 = ML[0 * 64 + lq], lj0 = ML[0 * 64 + 32 + lq];
        float mj1 = ML[1 * 64 + lq], lj1 = ML[1 * 64 + 32 + lq];
        float mj2 = ML[2 * 64 + lq], lj2 = ML[2 * 64 + 32 + lq];
        float mF = fmaxf(fmaxf(m2, mj0), fmaxf(mj1, mj2));
        float s0 = exp2f(m2 - mF);
        float t0 = exp2f(mj0 - mF), t1 = exp2f(mj1 - mF), t2 = exp2f(mj2 - mF);
        float inv = 1.f / (l * s0 + lj0 * t0 + lj1 * t1 + lj2 * t2);
        s0 *= inv; t0 *= inv; t1 *= inv; t2 *= inv;
        #pragma unroll
        for (int dt = 0; dt < 4; ++dt)
            #pragma unroll
            for (int rg = 0; rg < 16; ++rg) {
                int row = (rg & 3) + 8 * (rg >> 2) + 4 * h;
                float w0 = __shfl(s0, row), w1 = __shfl(t0, row);
                float w2 = __shfl(t1, row), w3 = __shfl(t2, row);
                float o = acc[dt][rg] * w0
                        + OB[0 * 4096 + row * 128 + lq + 32 * dt] * w1
                        + OB[1 * 4096 + row * 128 + lq + 32 * dt] * w2
                        + OB[2 * 4096 + row * 128 + lq + 32 * dt] * w3;
                outp[(size_t)(qbase + row) * NE + lq + 32 * dt] = o;
            }
    }
}

// ---------------------------------------------------------------------------
extern "C" void kernel_launch(void* const* d_in, const int* in_sizes, int n_in,
                              void* d_out, int out_size, void* d_ws, size_t ws_size,
                              hipStream_t stream)
{
    const float* x  = (const float*)d_in[0];
    const float* Wq = (const float*)d_in[1];
    const float* bq = (const float*)d_in[2];
    const float* Wk = (const float*)d_in[3];
    const float* bk = (const float*)d_in[4];
    const float* Wv = (const float*)d_in[5];
    const float* bv = (const float*)d_in[6];
    float* out = (float*)d_out;
    unsigned short* qkv = (unsigned short*)d_ws;   // 3*NROWS*NE*2 = 12.6 MB

    dim3 g1(NROWS / 32, 3, 2);
    qkv_kernel<<<g1, 256, 0, stream>>>(x, Wq, bq, Wk, bk, Wv, bv, qkv);

    attn_kernel<<<512, 256, 0, stream>>>(qkv, out);
}